// Round 12
// baseline (73.495 us; speedup 1.0000x reference)
//
#include <hip/hip_runtime.h>
#include <hip/hip_bf16.h>
#include <stdint.h>

typedef __attribute__((ext_vector_type(8))) short short8;
typedef __attribute__((ext_vector_type(4))) float f32x4;

constexpr int Tt = 8192, Kd = 1024, Nd = 1024, Gn = 8;
constexpr int BM = 128, BN = 128, BK = 64;
constexpr int NKT = Kd / BK; // 16 K-tiles

static __device__ __forceinline__ short f2bf(float x) {
    __hip_bfloat16 b = __float2bfloat16(x);
    return *reinterpret_cast<short*>(&b);
}

// raw barrier: own ds_writes drained; global loads stay IN FLIGHT (no vmcnt drain)
#define BAR() do { \
    asm volatile("s_waitcnt lgkmcnt(0)" ::: "memory"); \
    __builtin_amdgcn_s_barrier(); \
    __builtin_amdgcn_sched_barrier(0); \
} while (0)

// B depth-2 prefetch: 32 strided floats of W[k][n] (k-major, stride Nd) for col rr
#define LOAD_B(dst, kt) do { \
    const float* p = Wg + (size_t)((kt) * BK + kh * 32) * Nd + col0 + rr; \
    _Pragma("unroll") for (int j = 0; j < 32; ++j) dst[j] = p[(size_t)j * Nd]; \
} while (0)

// cvt + 4 swizzled ds_write_b128; slot = (kh*4+c) ^ (rr&7)  [R1/R4: 0 conflicts]
#define WRITE_B(src, buf) do { \
    const int s_ = rr & 7; \
    _Pragma("unroll") for (int c = 0; c < 4; ++c) { \
        short8 v_; \
        _Pragma("unroll") for (int j = 0; j < 8; ++j) v_[j] = f2bf(src[c * 8 + j]); \
        *(short8*)&Bs[buf][rr * 64 + (((kh * 4 + c) ^ s_) << 3)] = v_; \
    } \
} while (0)

__global__ __launch_bounds__(256, 2)
void gemm_fused(const float* __restrict__ H, const float* __restrict__ W,
                const int* __restrict__ counts, float* __restrict__ out)
{
    // bf16 LDS, 128B rows (64 shorts = 8 granules), dbuf, 64KB -> 2 blocks/CU
    __shared__ __align__(16) short As[2][BM * BK];
    __shared__ __align__(16) short Bs[2][BN * BK];

    const int tid = threadIdx.x;
    const int bid = blockIdx.x;
    const int wg = (bid & 7) * 64 + (bid >> 3);   // bijective XCD swizzle (512%8==0)
    const int mt = wg >> 3, nt = wg & 7;
    const int row0 = mt * BM, col0 = nt * BN;

    int g = 0;
    { int c = 0; for (int i = 0; i < Gn; ++i) { c += counts[i]; if (row0 >= c) g = i + 1; } }
    const float* __restrict__ Wg = W + (size_t)g * Kd * Nd;

    const int wid = tid >> 6, lane = tid & 63;
    const int wm = wid >> 1, wn = wid & 1;        // 2x2 waves, 64x64 each
    const int l15 = lane & 15, l4 = lane >> 4;

    const int rr = tid >> 1;                      // staging row (A) / col (B): 0..127
    const int kh = tid & 1;                       // k-half (32 elems)

    f32x4 acc[4][4];
#pragma unroll
    for (int i = 0; i < 4; ++i)
#pragma unroll
        for (int j = 0; j < 4; ++j) acc[i][j] = (f32x4)0.0f;

    f32x4 av[8];              // A depth-1: 32 consecutive floats
    float bv0[32], bv1[32];   // B depth-2: two NAMED sets (B(t) -> bv{t&1})

    auto load_a = [&](int kt) {                   // 8 coalesced dwordx4
        const float* p = H + (size_t)(row0 + rr) * Kd + kt * BK + kh * 32;
#pragma unroll
        for (int j = 0; j < 8; ++j) av[j] = *(const f32x4*)(p + j * 4);
    };
    auto write_a = [&](int buf) {                 // cvt + 4 swizzled ds_write_b128
        const int s = rr & 7;
#pragma unroll
        for (int c = 0; c < 4; ++c) {
            short8 v;
#pragma unroll
            for (int j = 0; j < 4; ++j) { v[j] = f2bf(av[2 * c][j]); v[4 + j] = f2bf(av[2 * c + 1][j]); }
            *(short8*)&As[buf][rr * 64 + (((kh * 4 + c) ^ s) << 3)] = v;
        }
    };

    auto compute = [&](int buf) {                 // R4-verified: 0 bank conflicts
#pragma unroll
        for (int ks = 0; ks < 2; ++ks) {
            short8 af[4], bf[4];
#pragma unroll
            for (int mi = 0; mi < 4; ++mi) {
                const int m = wm * 64 + mi * 16 + l15;
                af[mi] = *(const short8*)&As[buf][m * 64 + (((ks * 4 + l4) ^ (m & 7)) << 3)];
            }
#pragma unroll
            for (int ni = 0; ni < 4; ++ni) {
                const int n = wn * 64 + ni * 16 + l15;
                bf[ni] = *(const short8*)&Bs[buf][n * 64 + (((ks * 4 + l4) ^ (n & 7)) << 3)];
            }
#pragma unroll
            for (int mi = 0; mi < 4; ++mi)
#pragma unroll
                for (int ni = 0; ni < 4; ++ni)
                    acc[mi][ni] = __builtin_amdgcn_mfma_f32_16x16x32_bf16(
                        af[mi], bf[ni], acc[mi][ni], 0, 0, 0);
        }
    };

    // prologue: tile0 staged (latency exposed once); B(1)->bv1 issued, stays in flight
    LOAD_B(bv0, 0);
    load_a(0);
    WRITE_B(bv0, 0);
    write_a(0);
    LOAD_B(bv1, 1);
    BAR();

    // main loop, unrolled x2 for static reg-set choice (rule #20).
    // Phase kt: issue A(kt+1) + B(kt+2); compute(kt); write tile kt+1
    //   (B from the set loaded LAST phase -> its vmcnt wait is already satisfied;
    //    A's wait is covered by the 32-MFMA compute). Raw barrier, no vmcnt drain.
    for (int kt2 = 0; kt2 < NKT; kt2 += 2) {
        // even phase: compute buf0, stage tile kt2+1 -> buf1, B(kt2+2) -> bv0
        if (kt2 + 1 < NKT) load_a(kt2 + 1);
        if (kt2 + 2 < NKT) LOAD_B(bv0, kt2 + 2);
        compute(0);
        if (kt2 + 1 < NKT) { WRITE_B(bv1, 1); write_a(1); }
        BAR();
        // odd phase: compute buf1, stage tile kt2+2 -> buf0, B(kt2+3) -> bv1
        if (kt2 + 2 < NKT) load_a(kt2 + 2);
        if (kt2 + 3 < NKT) LOAD_B(bv1, kt2 + 3);
        compute(1);
        if (kt2 + 2 < NKT) { WRITE_B(bv0, 0); write_a(0); }
        BAR();
    }

    // epilogue: C/D layout col=lane&15, row=(lane>>4)*4+reg (m89-verified)
#pragma unroll
    for (int mi = 0; mi < 4; ++mi) {
        const int rbase = row0 + wm * 64 + mi * 16 + l4 * 4;
#pragma unroll
        for (int ni = 0; ni < 4; ++ni) {
            const int c = col0 + wn * 64 + ni * 16 + l15;
#pragma unroll
            for (int r = 0; r < 4; ++r)
                out[(size_t)(rbase + r) * Nd + c] = acc[mi][ni][r];
        }
    }
}

extern "C" void kernel_launch(void* const* d_in, const int* in_sizes, int n_in,
                              void* d_out, int out_size, void* d_ws, size_t ws_size,
                              hipStream_t stream) {
    const float* H = (const float*)d_in[0];
    const float* W = (const float*)d_in[1];
    const int* counts = (const int*)d_in[2];
    float* out = (float*)d_out;
    const int grid = (Tt / BM) * (Nd / BN);  // 64 * 8 = 512 blocks
    gemm_fused<<<grid, 256, 0, stream>>>(H, W, counts, out);
}